// Round 1
// baseline (253.961 us; speedup 1.0000x reference)
//
#include <hip/hip_runtime.h>
#include <math.h>

#define DIMS   256
#define KCODES 1024
#define NTOT   32768
#define TAU    4.0e-4f   // 3-term split distance-compare error <~6e-5; 6x margin

typedef __bf16 bf16x8 __attribute__((ext_vector_type(8)));
typedef float  f32x4  __attribute__((ext_vector_type(4)));

// ---- workspace layout (float indices; int views share) ----
#define WS_COMMIT   0          // float atomic
#define WS_FLAGCNT  1          // int atomic
#define WS_DECORR   2          // float atomic
#define WS_COLSUM   16         // float[256]
#define WS_COLSQ    272        // float[256]
#define WS_WSQ      1024       // float[1024]  (atomic-accumulated)
#define WS_XSQ      2048       // float[32768] (atomic-accumulated)
// memset zero region: bytes [0, 139264) covers all of the above
#define WS_FLAGS    34816      // int[32768]
#define WS_CAND1    67584      // float[8*32768]
#define WS_CAND2    329728     // float[8*32768]
#define WS_CANDI    591872     // int[8*32768]
#define WS_WP       854016     // bf16[524288] = 1 MB, fragment-ordered W

// ---- output layout (floats) ----
#define OUT_Q    0
#define OUT_IDX  8388608
#define OUT_SCAL 8421376

// Fragment layout (both Xp and Wp2), bf16 elems:
//   frag(bt, kt, wv, t, hl) base = ((((bt*8+kt)*2+wv)*4+t)*2+hl)*512
//   element (lane = kq*16+lc, e) at base + lane*8 + e
//   holds hi/lo bf16 of src[row = bt*128+wv*64+t*16+lc][k = kt*32+kq*8+e]
// => for fixed (bt,kt) the 16 frags (wv,t,hl) are 8192 contiguous elems (16 KB).

// ---------- fused prep ----------
// blocks [0,1024): pack X | [1024,1056): pack W | [1056,1064): colstats | [1064,1192): cov
__global__ __launch_bounds__(256) void prep_kernel(const float* __restrict__ X,
                                                   const float* __restrict__ W,
                                                   __bf16* __restrict__ Xp,
                                                   __bf16* __restrict__ Wp2,
                                                   float* ws) {
  int b = blockIdx.x;
  int tid = threadIdx.x;
  if (b < 1056) {
    bool isW = b >= 1024;
    const float* src = isW ? W : X;
    __bf16* dst = isW ? Wp2 : Xp;
    int sqoff = isW ? WS_WSQ : WS_XSQ;
    int bb = isW ? b - 1024 : b;
    int kt = tid >> 5, mtl = (tid >> 4) & 1, lc = tid & 15;
    int row = bb * 32 + mtl * 16 + lc;
    int bt = row >> 7, c = row & 127;
    int wv = c >> 6, t = (c >> 4) & 3;
    size_t hibase = ((((size_t)(bt * 8 + kt) * 2 + wv) * 4 + t) * 2) * 512;
    const float* s = src + (size_t)row * DIMS + kt * 32;
    float sq = 0.f;
    #pragma unroll
    for (int kq = 0; kq < 4; kq++) {
      float4 u = *(const float4*)(s + kq * 8);
      float4 v = *(const float4*)(s + kq * 8 + 4);
      float f[8] = {u.x, u.y, u.z, u.w, v.x, v.y, v.z, v.w};
      bf16x8 hi, lo;
      #pragma unroll
      for (int e = 0; e < 8; e++) {
        __bf16 h = (__bf16)f[e];
        hi[e] = h;
        lo[e] = (__bf16)(f[e] - (float)h);
        sq = fmaf(f[e], f[e], sq);
      }
      size_t off = (size_t)(kq * 16 + lc) * 8;
      *(bf16x8*)&dst[hibase + off] = hi;
      *(bf16x8*)&dst[hibase + 512 + off] = lo;
    }
    atomicAdd(&ws[sqoff + row], sq);
  } else if (b < 1064) {
    // colstats: 8 blocks x 128 rows
    int d = tid;
    int r0 = (b - 1056) * 128;
    float s = 0.f, sq = 0.f;
    #pragma unroll 8
    for (int k = 0; k < 128; k++) {
      float v = W[(size_t)(r0 + k) * DIMS + d];
      s += v;
      sq = fmaf(v, v, sq);
    }
    atomicAdd(&ws[WS_COLSUM + d], s);
    atomicAdd(&ws[WS_COLSQ + d], sq);
  } else {
    // cov: 128 blocks x 2 columns, self-contained means
    __shared__ float wi_s[2][KCODES];
    __shared__ float red2[256];
    __shared__ float mi_s[2];
    __shared__ float red[4];
    int i0 = (b - 1064) * 2;
    int rr = tid >> 1, cc = tid & 1;
    #pragma unroll
    for (int q = 0; q < 8; q++) {
      int row = q * 128 + rr;
      wi_s[cc][row] = W[(size_t)row * DIMS + i0 + cc];
    }
    __syncthreads();
    float pm = 0.f;
    #pragma unroll
    for (int q = 0; q < 8; q++) pm += wi_s[cc][rr * 8 + q];
    red2[tid] = pm;
    __syncthreads();
    if (tid < 2) {
      float s = 0.f;
      for (int k = tid; k < 256; k += 2) s += red2[k];
      mi_s[tid] = s * (1.0f / 1024.0f);
    }
    int j = tid;
    float a0 = 0.f, a1 = 0.f, sj = 0.f;
    for (int k = 0; k < KCODES; k += 4) {
      #pragma unroll
      for (int u = 0; u < 4; u++) {
        float wj = W[(size_t)(k + u) * DIMS + j];
        a0 = fmaf(wi_s[0][k + u], wj, a0);
        a1 = fmaf(wi_s[1][k + u], wj, a1);
        sj += wj;
      }
    }
    __syncthreads();  // mi_s ready
    const float inv = 1.0f / 1024.0f;
    float mj = sj * inv;
    float v = 0.f;
    float c0 = a0 * inv - mi_s[0] * mj;
    if (i0 != j) v = fmaf(c0, c0, v);
    float c1 = a1 * inv - mi_s[1] * mj;
    if (i0 + 1 != j) v = fmaf(c1, c1, v);
    #pragma unroll
    for (int m = 32; m >= 1; m >>= 1) v += __shfl_xor(v, m);
    if ((j & 63) == 0) red[j >> 6] = v;
    __syncthreads();
    if (j == 0) atomicAdd(&ws[WS_DECORR], (red[0] + red[1]) + (red[2] + red[3]));
  }
}

// ---------- pass1 v2: LDS-staged, counted-vmcnt phase pipeline ----------
// Tile 256 rows x 128 cols, 512 threads (8 waves: wm=wave>>1 in 0..3 row strips
// of 64, wn=wave&1 in 0..1 col strips of 64). K-loop = 8 kt steps of 32 dims
// (hi+lo). 3 LDS slots x 48 KB (A 32 KB + B 16 KB), fragment-linear so
// global_load_lds(16B) is legal and ds_read_b128 is bank-conflict-free.
// Pipeline invariants:
//   prologue: issue tiles 0,1,2 (6 loads each); vmcnt(12) retires tile 0.
//   during kt: issue tile kt+2 into slot (kt+2)%3 == slot freed at end of kt-1
//              (safe: all reads of it completed before kt-1's final barrier).
//   end of kt: vmcnt(6) retires tile kt+1 (only kt+2's 6 loads stay in flight);
//              never drains to 0 in steady state (T4). kt==6 -> vmcnt(0) tail.
//   NO other vector-memory ops inside the loop (would corrupt vmcnt counts).
// Numerics: identical MFMA sequence per accumulator as previous version
// (kt ascending; per (mt,nt): hi*hi, hi*lo, lo*hi) -> bit-identical distances.
__device__ __forceinline__ void stage16(const __bf16* g, __bf16* l) {
  __builtin_amdgcn_global_load_lds(
      (const __attribute__((address_space(1))) void*)g,
      (__attribute__((address_space(3))) void*)l, 16, 0, 0);
}

#define STAGE_PIECE(T, J) do {                                                    \
    int _s = (T) % 3;                                                             \
    if ((J) < 4) {                                                                \
      int _c = (J) >> 1, _h = (J) & 1;                                            \
      stage16(Xp + (size_t)((2 * bm + _c) * 8 + (T)) * 8192 + _h * 4096 + tid * 8,\
              buf + _s * 24576 + _c * 8192 + _h * 4096 + tid * 8);                \
    } else {                                                                      \
      int _h = (J) - 4;                                                           \
      stage16(Wp2 + (size_t)(bn * 8 + (T)) * 8192 + _h * 4096 + tid * 8,          \
              buf + _s * 24576 + 16384 + _h * 4096 + tid * 8);                    \
    }                                                                             \
  } while (0)

__global__ __launch_bounds__(512, 2) void pass1_kernel(const __bf16* __restrict__ Xp,
                                                       const __bf16* __restrict__ Wp2,
                                                       float* ws) {
  __shared__ __align__(16) __bf16 buf[73728];  // 3 slots x 24576 elems = 144 KB
  __shared__ float wsqs[128];
  __shared__ float d1L[512];
  __shared__ float d2L[512];
  __shared__ int   i1L[512];

  int tid = threadIdx.x;
  int lane = tid & 63, wave = tid >> 6;
  int wm = wave >> 1, wn = wave & 1;   // wm: 64-row strip 0..3, wn: 64-col strip 0..1
  int quad = lane >> 4, col = lane & 15;
  int l = blockIdx.x;
  // XCD-chunked bijective swizzle: XCD x gets bm in [16x,16x+16) for all bn
  // -> resident working set per XCD L2: 16 A-panels (4 MB) + full B (1 MB hot).
  int swz = (l & 7) * 128 + (l >> 3);
  int bm = swz >> 3;   // 0..127 (256-row tile)
  int bn = swz & 7;    // 0..7   (128-col tile)
  int cb = bn * 128;

  f32x4 acc[4][4];
  #pragma unroll
  for (int i = 0; i < 4; i++)
    #pragma unroll
    for (int j = 0; j < 4; j++) acc[i][j] = (f32x4){0.f, 0.f, 0.f, 0.f};

  // W norms for this col tile (uniform across waves so vmcnt counts stay uniform;
  // duplicate same-value LDS writes are benign). This is the OLDEST vmem op ->
  // retired by the prologue vmcnt(12).
  wsqs[tid & 127] = ws[WS_WSQ + cb + (tid & 127)];
  asm volatile("" ::: "memory");

  // prologue: stage tiles 0,1,2
  #pragma unroll
  for (int t = 0; t < 3; t++) {
    STAGE_PIECE(t, 0); STAGE_PIECE(t, 1); STAGE_PIECE(t, 2);
    STAGE_PIECE(t, 3); STAGE_PIECE(t, 4); STAGE_PIECE(t, 5);
  }
  asm volatile("s_waitcnt vmcnt(12)" ::: "memory");  // tile 0 (and wsqs) retired
  __builtin_amdgcn_s_barrier();

  #pragma unroll
  for (int kt = 0; kt < 8; kt++) {
    const __bf16* bsl = buf + (kt % 3) * 24576 + lane * 8;
    bf16x8 Bf[4][2];
    #pragma unroll
    for (int p = 0; p < 4; p++) {
      // ds reads for this phase (slot data ready since kt start; overlaps
      // other waves' previous-phase MFMAs)
      bf16x8 A0 = *(const bf16x8*)(bsl + wm * 4096 + (p * 2 + 0) * 512);
      bf16x8 A1 = *(const bf16x8*)(bsl + wm * 4096 + (p * 2 + 1) * 512);
      if (p == 0) {
        #pragma unroll
        for (int nt = 0; nt < 4; nt++) {
          Bf[nt][0] = *(const bf16x8*)(bsl + 16384 + wn * 4096 + (nt * 2 + 0) * 512);
          Bf[nt][1] = *(const bf16x8*)(bsl + 16384 + wn * 4096 + (nt * 2 + 1) * 512);
        }
      }
      // interleaved prefetch of tile kt+2 (2/2/1/1 across phases)
      if (kt + 2 < 8) {
        if (p == 0) { STAGE_PIECE(kt + 2, 0); STAGE_PIECE(kt + 2, 1); }
        if (p == 1) { STAGE_PIECE(kt + 2, 2); STAGE_PIECE(kt + 2, 3); }
        if (p == 2) { STAGE_PIECE(kt + 2, 4); }
        if (p == 3) { STAGE_PIECE(kt + 2, 5); }
      }
      // once per K-tile: retire tile kt+1 before the barriers that precede
      // its first ds_read (kt+1 phase 0); leave kt+2's 6 loads in flight.
      if (p == 3 && kt < 7) {
        if (kt <= 5) asm volatile("s_waitcnt vmcnt(6)" ::: "memory");
        else         asm volatile("s_waitcnt vmcnt(0)" ::: "memory");
      }
      __builtin_amdgcn_s_barrier();
      asm volatile("s_waitcnt lgkmcnt(0)" ::: "memory");
      __builtin_amdgcn_sched_barrier(0);  // rule #18: fence MFMA below the wait
      __builtin_amdgcn_s_setprio(1);
      #pragma unroll
      for (int nt = 0; nt < 4; nt++) {
        acc[p][nt] = __builtin_amdgcn_mfma_f32_16x16x32_bf16(A0, Bf[nt][0], acc[p][nt], 0, 0, 0);
        acc[p][nt] = __builtin_amdgcn_mfma_f32_16x16x32_bf16(A0, Bf[nt][1], acc[p][nt], 0, 0, 0);
        acc[p][nt] = __builtin_amdgcn_mfma_f32_16x16x32_bf16(A1, Bf[nt][0], acc[p][nt], 0, 0, 0);
      }
      __builtin_amdgcn_s_setprio(0);
      __builtin_amdgcn_s_barrier();
    }
  }

  // epilogue: per-row (best, 2nd, idx); C layout: row = quad*4 + reg, col = lane&15
  #pragma unroll
  for (int mt = 0; mt < 4; mt++) {
    #pragma unroll
    for (int r = 0; r < 4; r++) {
      float d1 = 3.0e38f, d2 = 3.0e38f;
      int i1 = 0;
      #pragma unroll
      for (int nt = 0; nt < 4; nt++) {
        int lc = wn * 64 + nt * 16 + col;
        float d = wsqs[lc] - 2.0f * acc[mt][nt][r];
        int g = cb + lc;
        if (d < d1) { d2 = d1; d1 = d; i1 = g; }
        else if (d < d2) d2 = d;
      }
      #pragma unroll
      for (int m = 1; m < 16; m <<= 1) {
        float od1 = __shfl_xor(d1, m);
        int oi1 = __shfl_xor(i1, m);
        float od2 = __shfl_xor(d2, m);
        if (od1 < d1 || (od1 == d1 && oi1 < i1)) {
          d2 = fminf(d1, fminf(d2, od2));
          d1 = od1; i1 = oi1;
        } else {
          d2 = fminf(od1, fminf(d2, od2));
        }
      }
      if (col == 0) {
        int lr = wm * 64 + mt * 16 + quad * 4 + r;  // 0..255
        d1L[lr * 2 + wn] = d1;
        d2L[lr * 2 + wn] = d2;
        i1L[lr * 2 + wn] = i1;
      }
    }
  }
  __syncthreads();
  if (tid < 256) {
    float a1 = d1L[tid * 2], a2 = d2L[tid * 2];
    int ai = i1L[tid * 2];
    float b1 = d1L[tid * 2 + 1], b2 = d2L[tid * 2 + 1];
    int bi = i1L[tid * 2 + 1];
    float m1, m2; int mi;
    if (b1 < a1 || (b1 == a1 && bi < ai)) { m1 = b1; mi = bi; m2 = fminf(a1, b2); }
    else { m1 = a1; mi = ai; m2 = fminf(b1, a2); }
    int o = bn * NTOT + bm * 256 + tid;
    ws[WS_CAND1 + o] = m1;
    ws[WS_CAND2 + o] = m2;
    ((int*)ws)[WS_CANDI + o] = mi;
  }
}

// ---------- pass2: merge candidates; idx, commit, flags; fused quant gather ----------
__global__ __launch_bounds__(256) void pass2_kernel(const float* __restrict__ W,
                                                    float* __restrict__ outQ,
                                                    float* __restrict__ outIdx, float* ws) {
  __shared__ int idx_s[256];
  int tid = threadIdx.x;
  int row = blockIdx.x * 256 + tid;
  const float* c1 = ws + WS_CAND1;
  const float* c2 = ws + WS_CAND2;
  const int* ci = (const int*)ws + WS_CANDI;
  float m1 = 3.0e38f, m2 = 3.0e38f;
  int mi = 0;
  #pragma unroll
  for (int b = 0; b < 8; b++) {
    int o = b * NTOT + row;
    float b1 = c1[o], b2 = c2[o];
    int bi = ci[o];
    if (b1 < m1 || (b1 == m1 && bi < mi)) { m2 = fminf(m1, b2); m1 = b1; mi = bi; }
    else { m2 = fminf(m2, b1); }
  }
  outIdx[row] = (float)mi;
  idx_s[tid] = mi;
  int* wsI = (int*)ws;
  if (m2 - m1 < TAU) {
    int p = atomicAdd(&wsI[WS_FLAGCNT], 1);
    wsI[WS_FLAGS + p] = row;
  }
  float partial = ws[WS_XSQ + row] + m1;
  #pragma unroll
  for (int m = 32; m >= 1; m >>= 1) partial += __shfl_xor(partial, m);
  if ((tid & 63) == 0) atomicAdd(&ws[WS_COMMIT], partial);
  __syncthreads();
  int wave = tid >> 6, lane = tid & 63;
  int rowBase = blockIdx.x * 256;
  #pragma unroll 4
  for (int i = 0; i < 64; i++) {
    int rl = wave * 64 + i;
    int ix = idx_s[rl];
    float4 v = ((const float4*)(W + (size_t)ix * DIMS))[lane];
    ((float4*)(outQ + (size_t)(rowBase + rl) * DIMS))[lane] = v;
  }
}

// ---------- f64 refinement (blocks 0..511) + fused scalar finalize (block 512) ----------
__global__ __launch_bounds__(256) void refine_kernel(const float* __restrict__ X,
                                                     const float* __restrict__ W,
                                                     float* __restrict__ outQ,
                                                     float* __restrict__ outIdx, float* ws,
                                                     const float* __restrict__ U,
                                                     float* __restrict__ out) {
  __shared__ float xs[DIMS];
  __shared__ double dm[256];
  __shared__ int im[256];
  __shared__ int chosen;
  int tid = threadIdx.x;
  if (blockIdx.x == 512) {
    // ---- finalize ----
    __shared__ float red[256];
    float s = 0.f;
    for (int e = tid; e < KCODES; e += 256) s += U[e] + 1e-5f;
    red[tid] = s;
    __syncthreads();
    for (int st = 128; st >= 1; st >>= 1) {
      if (tid < st) red[tid] += red[tid + st];
      __syncthreads();
    }
    float S = red[0];
    __syncthreads();
    float denom = fmaxf(S, 1e-5f * 1024.0f);
    float h = 0.f;
    for (int e = tid; e < KCODES; e += 256) {
      float p = (U[e] + 1e-5f) / denom;
      h += p * logf(p + 1e-5f);
    }
    red[tid] = h;
    __syncthreads();
    for (int st = 128; st >= 1; st >>= 1) {
      if (tid < st) red[tid] += red[tid + st];
      __syncthreads();
    }
    float H = -red[0] / 6.93147180559945f;  // ln(1024)
    __syncthreads();
    float m = ws[WS_COLSUM + tid] * (1.0f / 1024.0f);
    float var = ws[WS_COLSQ + tid] * (1.0f / 1024.0f) - m * m;
    float r = 0.05f - var;
    red[tid] = r > 0.f ? r : 0.f;
    __syncthreads();
    for (int st = 128; st >= 1; st >>= 1) {
      if (tid < st) red[tid] += red[tid + st];
      __syncthreads();
    }
    if (tid == 0) {
      float varloss = 1e-3f * (red[0] / 256.0f);
      float gap = H < 0.5f ? (0.5f - H) : (H > 0.9f ? (H - 0.9f) : 0.0f);
      float entloss = 0.1f * gap * gap;
      float commit = 0.25f * ws[WS_COMMIT] / 8388608.0f;
      float dec = 1e-3f * ws[WS_DECORR] / 65536.0f;
      float* sc = out + OUT_SCAL;
      sc[0] = commit + entloss + varloss + dec;
      sc[1] = commit;
      sc[2] = entloss;
      sc[3] = varloss;
      sc[4] = dec;
      sc[5] = H;
    }
    return;
  }
  const int* wsI = (const int*)ws;
  int cnt = wsI[WS_FLAGCNT];
  const int* list = wsI + WS_FLAGS;
  for (int f = blockIdx.x; f < cnt; f += 512) {
    int row = list[f];
    __syncthreads();
    if (tid < 64) ((float4*)xs)[tid] = ((const float4*)(X + (size_t)row * DIMS))[tid];
    __syncthreads();
    double bd = 1.0e300;
    int bi = 0;
    for (int jj = 0; jj < 4; jj++) {
      int c = tid + 256 * jj;
      double a0 = 0.0, a1 = 0.0, a2 = 0.0, a3 = 0.0;
      const float* wr = W + (size_t)c * DIMS;
      #pragma unroll 4
      for (int d4 = 0; d4 < 64; d4++) {
        float4 w = ((const float4*)wr)[d4];
        float4 x = ((const float4*)xs)[d4];
        double e0 = (double)x.x - (double)w.x;
        double e1 = (double)x.y - (double)w.y;
        double e2 = (double)x.z - (double)w.z;
        double e3 = (double)x.w - (double)w.w;
        a0 += e0 * e0; a1 += e1 * e1; a2 += e2 * e2; a3 += e3 * e3;
      }
      double s = (a0 + a1) + (a2 + a3);
      if (s < bd) { bd = s; bi = c; }
    }
    dm[tid] = bd; im[tid] = bi;
    __syncthreads();
    for (int st = 128; st >= 1; st >>= 1) {
      if (tid < st) {
        if (dm[tid + st] < dm[tid] || (dm[tid + st] == dm[tid] && im[tid + st] < im[tid])) {
          dm[tid] = dm[tid + st]; im[tid] = im[tid + st];
        }
      }
      __syncthreads();
    }
    if (tid == 0) { chosen = im[0]; outIdx[row] = (float)im[0]; }
    __syncthreads();
    int ix = chosen;
    if (tid < 64)
      ((float4*)(outQ + (size_t)row * DIMS))[tid] = ((const float4*)(W + (size_t)ix * DIMS))[tid];
  }
}

extern "C" void kernel_launch(void* const* d_in, const int* in_sizes, int n_in, void* d_out,
                              int out_size, void* d_ws, size_t ws_size, hipStream_t stream) {
  const float* X = (const float*)d_in[0];
  const float* W = (const float*)d_in[1];
  const float* U = (const float*)d_in[2];
  float* out = (float*)d_out;
  float* ws = (float*)d_ws;
  __bf16* Xp = (__bf16*)(out + OUT_Q);       // 33.55 MB, overwritten by pass2's gather
  __bf16* Wp2 = (__bf16*)(ws + WS_WP);       // 1 MB, fragment-ordered

  hipMemsetAsync(d_ws, 0, 139264, stream);
  prep_kernel<<<1192, 256, 0, stream>>>(X, W, Xp, Wp2, ws);
  pass1_kernel<<<1024, 512, 0, stream>>>(Xp, Wp2, ws);
  pass2_kernel<<<NTOT / 256, 256, 0, stream>>>(W, out + OUT_Q, out + OUT_IDX, ws);
  refine_kernel<<<513, 256, 0, stream>>>(X, W, out + OUT_Q, out + OUT_IDX, ws, U, out);
}

// Round 2
// 237.049 us; speedup vs baseline: 1.0713x; 1.0713x over previous
//
#include <hip/hip_runtime.h>
#include <math.h>

#define DIMS   256
#define KCODES 1024
#define NTOT   32768
#define TAU    4.0e-4f   // 3-term split distance-compare error <~6e-5; 6x margin

typedef __bf16 bf16x8 __attribute__((ext_vector_type(8)));
typedef float  f32x4  __attribute__((ext_vector_type(4)));

// ---- workspace layout (float indices; int views share) ----
#define WS_COMMIT   0          // float atomic
#define WS_FLAGCNT  1          // int atomic
#define WS_DECORR   2          // float atomic
#define WS_COLSUM   16         // float[256]
#define WS_COLSQ    272        // float[256]
#define WS_WSQ      1024       // float[1024]  (atomic-accumulated)
#define WS_XSQ      2048       // float[32768] (atomic-accumulated)
// memset zero region: bytes [0, 139264) covers all of the above
#define WS_FLAGS    34816      // int[32768]
#define WS_CAND1    67584      // float[8*32768] (slots 0..3 used)
#define WS_CAND2    329728     // float[8*32768]
#define WS_CANDI    591872     // int[8*32768]
#define WS_WP       854016     // bf16[524288] = 1 MB, fragment-ordered W

// ---- output layout (floats) ----
#define OUT_Q    0
#define OUT_IDX  8388608
#define OUT_SCAL 8421376

// Fragment layout (both Xp and Wp2), bf16 elems:
//   frag(bt, kt, wv, t, hl) base = ((((bt*8+kt)*2+wv)*4+t)*2+hl)*512
//   element (lane = kq*16+lc, e) at base + lane*8 + e
//   holds hi/lo bf16 of src[row = bt*128+wv*64+t*16+lc][k = kt*32+kq*8+e]
// => for fixed (bt,kt) the 16 frags (wv,t,hl) are 8192 contiguous elems (16 KB).

// ---------- fused prep ----------
// blocks [0,1024): pack X | [1024,1056): pack W | [1056,1064): colstats | [1064,1192): cov
__global__ __launch_bounds__(256) void prep_kernel(const float* __restrict__ X,
                                                   const float* __restrict__ W,
                                                   __bf16* __restrict__ Xp,
                                                   __bf16* __restrict__ Wp2,
                                                   float* ws) {
  int b = blockIdx.x;
  int tid = threadIdx.x;
  if (b < 1056) {
    bool isW = b >= 1024;
    const float* src = isW ? W : X;
    __bf16* dst = isW ? Wp2 : Xp;
    int sqoff = isW ? WS_WSQ : WS_XSQ;
    int bb = isW ? b - 1024 : b;
    int kt = tid >> 5, mtl = (tid >> 4) & 1, lc = tid & 15;
    int row = bb * 32 + mtl * 16 + lc;
    int bt = row >> 7, c = row & 127;
    int wv = c >> 6, t = (c >> 4) & 3;
    size_t hibase = ((((size_t)(bt * 8 + kt) * 2 + wv) * 4 + t) * 2) * 512;
    const float* s = src + (size_t)row * DIMS + kt * 32;
    float sq = 0.f;
    #pragma unroll
    for (int kq = 0; kq < 4; kq++) {
      float4 u = *(const float4*)(s + kq * 8);
      float4 v = *(const float4*)(s + kq * 8 + 4);
      float f[8] = {u.x, u.y, u.z, u.w, v.x, v.y, v.z, v.w};
      bf16x8 hi, lo;
      #pragma unroll
      for (int e = 0; e < 8; e++) {
        __bf16 h = (__bf16)f[e];
        hi[e] = h;
        lo[e] = (__bf16)(f[e] - (float)h);
        sq = fmaf(f[e], f[e], sq);
      }
      size_t off = (size_t)(kq * 16 + lc) * 8;
      *(bf16x8*)&dst[hibase + off] = hi;
      *(bf16x8*)&dst[hibase + 512 + off] = lo;
    }
    atomicAdd(&ws[sqoff + row], sq);
  } else if (b < 1064) {
    // colstats: 8 blocks x 128 rows
    int d = tid;
    int r0 = (b - 1056) * 128;
    float s = 0.f, sq = 0.f;
    #pragma unroll 8
    for (int k = 0; k < 128; k++) {
      float v = W[(size_t)(r0 + k) * DIMS + d];
      s += v;
      sq = fmaf(v, v, sq);
    }
    atomicAdd(&ws[WS_COLSUM + d], s);
    atomicAdd(&ws[WS_COLSQ + d], sq);
  } else {
    // cov: 128 blocks x 2 columns, self-contained means
    __shared__ float wi_s[2][KCODES];
    __shared__ float red2[256];
    __shared__ float mi_s[2];
    __shared__ float red[4];
    int i0 = (b - 1064) * 2;
    int rr = tid >> 1, cc = tid & 1;
    #pragma unroll
    for (int q = 0; q < 8; q++) {
      int row = q * 128 + rr;
      wi_s[cc][row] = W[(size_t)row * DIMS + i0 + cc];
    }
    __syncthreads();
    float pm = 0.f;
    #pragma unroll
    for (int q = 0; q < 8; q++) pm += wi_s[cc][rr * 8 + q];
    red2[tid] = pm;
    __syncthreads();
    if (tid < 2) {
      float s = 0.f;
      for (int k = tid; k < 256; k += 2) s += red2[k];
      mi_s[tid] = s * (1.0f / 1024.0f);
    }
    int j = tid;
    float a0 = 0.f, a1 = 0.f, sj = 0.f;
    for (int k = 0; k < KCODES; k += 4) {
      #pragma unroll
      for (int u = 0; u < 4; u++) {
        float wj = W[(size_t)(k + u) * DIMS + j];
        a0 = fmaf(wi_s[0][k + u], wj, a0);
        a1 = fmaf(wi_s[1][k + u], wj, a1);
        sj += wj;
      }
    }
    __syncthreads();  // mi_s ready
    const float inv = 1.0f / 1024.0f;
    float mj = sj * inv;
    float v = 0.f;
    float c0 = a0 * inv - mi_s[0] * mj;
    if (i0 != j) v = fmaf(c0, c0, v);
    float c1 = a1 * inv - mi_s[1] * mj;
    if (i0 + 1 != j) v = fmaf(c1, c1, v);
    #pragma unroll
    for (int m = 32; m >= 1; m >>= 1) v += __shfl_xor(v, m);
    if ((j & 63) == 0) red[j >> 6] = v;
    __syncthreads();
    if (j == 0) atomicAdd(&ws[WS_DECORR], (red[0] + red[1]) + (red[2] + red[3]));
  }
}

// ---------- pass1 v3: 256x256 tile, LDS double-buffer, ONE barrier per kt ----------
// 512 threads = 8 waves: wm=wave>>2 (128-row strip), wn=wave&3 (64-col strip).
// Per wave: 128x64 output, acc[8][4] f32x4. K-loop: 8 kt x 32 dims (hi+lo).
// Per kt per wave: 8 B-reads (held in regs) + 4 phases x {4 A-reads, 24 MFMA}.
// No intra-kt barriers: waves skew naturally; one wave's LDS-read latency hides
// under the other SIMD-resident wave's MFMA cluster (m114 co-schedule). The only
// barrier is the end-of-kt slot-swap (correctness: vmcnt(0) first so each wave's
// own staging loads have landed; barrier then makes all waves' staging visible).
// Staging: tile kt+1 issued at kt top (full-kt lead time >> L2 latency).
// Numerics: identical MFMA chain per (mt,nt) as v1/v2 -> bit-identical distances.
__device__ __forceinline__ void stage16(const __bf16* g, __bf16* l) {
  __builtin_amdgcn_global_load_lds(
      (const __attribute__((address_space(1))) void*)g,
      (__attribute__((address_space(3))) void*)l, 16, 0, 0);
}

// LDS slot layout (bf16 elems): A: [c][wv][t][hl][512] at 0..16384,
//                               B: same shape at 16384..32768
#define STAGE_TILE(T) do {                                                          \
    __bf16* _d = &buf[(T) & 1][0];                                                  \
    const size_t _tb = (size_t)(T) * 8192;                                          \
    stage16(Xp + (size_t)(bm * 2 + 0) * 65536 + _tb + 0 * 4096 + tid * 8,           \
            _d + 0 * 8192 + 0 * 4096 + tid * 8);                                    \
    stage16(Xp + (size_t)(bm * 2 + 0) * 65536 + _tb + 1 * 4096 + tid * 8,           \
            _d + 0 * 8192 + 1 * 4096 + tid * 8);                                    \
    stage16(Xp + (size_t)(bm * 2 + 1) * 65536 + _tb + 0 * 4096 + tid * 8,           \
            _d + 1 * 8192 + 0 * 4096 + tid * 8);                                    \
    stage16(Xp + (size_t)(bm * 2 + 1) * 65536 + _tb + 1 * 4096 + tid * 8,           \
            _d + 1 * 8192 + 1 * 4096 + tid * 8);                                    \
    stage16(Wp2 + (size_t)(bn * 2 + 0) * 65536 + _tb + 0 * 4096 + tid * 8,          \
            _d + 16384 + 0 * 8192 + 0 * 4096 + tid * 8);                            \
    stage16(Wp2 + (size_t)(bn * 2 + 0) * 65536 + _tb + 1 * 4096 + tid * 8,          \
            _d + 16384 + 0 * 8192 + 1 * 4096 + tid * 8);                            \
    stage16(Wp2 + (size_t)(bn * 2 + 1) * 65536 + _tb + 0 * 4096 + tid * 8,          \
            _d + 16384 + 1 * 8192 + 0 * 4096 + tid * 8);                            \
    stage16(Wp2 + (size_t)(bn * 2 + 1) * 65536 + _tb + 1 * 4096 + tid * 8,          \
            _d + 16384 + 1 * 8192 + 1 * 4096 + tid * 8);                            \
  } while (0)

__global__ __launch_bounds__(512, 2) void pass1_kernel(const __bf16* __restrict__ Xp,
                                                       const __bf16* __restrict__ Wp2,
                                                       float* ws) {
  __shared__ __align__(16) __bf16 buf[2][32768];  // 2 slots x 64 KB = 128 KB
  __shared__ float wsqs[256];
  __shared__ float d1L[256][4];
  __shared__ float d2L[256][4];
  __shared__ int   i1L[256][4];

  int tid = threadIdx.x;
  int lane = tid & 63, wave = tid >> 6;
  int wm = wave >> 2, wn = wave & 3;   // wm: 128-row strip 0..1, wn: 64-col strip 0..3
  int quad = lane >> 4, col = lane & 15;
  int l = blockIdx.x;
  // XCD-chunked bijective swizzle (nwg=512 = 8*64): XCD x gets bm in [16x,16x+16)
  int swz = (l & 7) * 64 + (l >> 3);
  int bm = swz >> 2;   // 0..127 (256-row tile)
  int bn = swz & 3;    // 0..3   (256-col tile)
  int cb = bn * 256;

  f32x4 acc[8][4];
  #pragma unroll
  for (int i = 0; i < 8; i++)
    #pragma unroll
    for (int j = 0; j < 4; j++) acc[i][j] = (f32x4){0.f, 0.f, 0.f, 0.f};

  // W norms for this col tile (dup writes benign; oldest vmem op -> retired by
  // the prologue vmcnt(8) along with tile 0).
  wsqs[tid & 255] = ws[WS_WSQ + cb + (tid & 255)];
  asm volatile("" ::: "memory");

  // prologue: stage tiles 0 and 1 (slots 0,1); retire wsqs + tile 0
  STAGE_TILE(0);
  STAGE_TILE(1);
  asm volatile("s_waitcnt vmcnt(8)" ::: "memory");
  __builtin_amdgcn_s_barrier();

  #pragma unroll 2
  for (int kt = 0; kt < 8; kt++) {
    const __bf16* bs = &buf[kt & 1][0];
    if (kt >= 1 && kt < 7) STAGE_TILE(kt + 1);  // into slot (kt+1)&1, freed at end of kt-1
    // B fragments for this kt, held in registers across all 4 phases
    bf16x8 Bf[4][2];
    const __bf16* bB = bs + 16384 + (wn >> 1) * 8192 + (wn & 1) * 4096 + lane * 8;
    #pragma unroll
    for (int nt = 0; nt < 4; nt++) {
      Bf[nt][0] = *(const bf16x8*)(bB + nt * 1024);
      Bf[nt][1] = *(const bf16x8*)(bB + nt * 1024 + 512);
    }
    const __bf16* bA = bs + wm * 8192 + lane * 8;
    #pragma unroll
    for (int p = 0; p < 4; p++) {
      // A fragments for mt = 2p, 2p+1 (offset = mt*1024 elems, +512 for lo)
      bf16x8 A00 = *(const bf16x8*)(bA + (2 * p + 0) * 1024);
      bf16x8 A01 = *(const bf16x8*)(bA + (2 * p + 0) * 1024 + 512);
      bf16x8 A10 = *(const bf16x8*)(bA + (2 * p + 1) * 1024);
      bf16x8 A11 = *(const bf16x8*)(bA + (2 * p + 1) * 1024 + 512);
      __builtin_amdgcn_sched_barrier(0);  // cluster: reads above, MFMAs below
      __builtin_amdgcn_s_setprio(1);
      #pragma unroll
      for (int nt = 0; nt < 4; nt++) {
        acc[2 * p + 0][nt] = __builtin_amdgcn_mfma_f32_16x16x32_bf16(A00, Bf[nt][0], acc[2 * p + 0][nt], 0, 0, 0);
        acc[2 * p + 0][nt] = __builtin_amdgcn_mfma_f32_16x16x32_bf16(A00, Bf[nt][1], acc[2 * p + 0][nt], 0, 0, 0);
        acc[2 * p + 0][nt] = __builtin_amdgcn_mfma_f32_16x16x32_bf16(A01, Bf[nt][0], acc[2 * p + 0][nt], 0, 0, 0);
        acc[2 * p + 1][nt] = __builtin_amdgcn_mfma_f32_16x16x32_bf16(A10, Bf[nt][0], acc[2 * p + 1][nt], 0, 0, 0);
        acc[2 * p + 1][nt] = __builtin_amdgcn_mfma_f32_16x16x32_bf16(A10, Bf[nt][1], acc[2 * p + 1][nt], 0, 0, 0);
        acc[2 * p + 1][nt] = __builtin_amdgcn_mfma_f32_16x16x32_bf16(A11, Bf[nt][0], acc[2 * p + 1][nt], 0, 0, 0);
      }
      __builtin_amdgcn_s_setprio(0);
    }
    if (kt < 7) {
      // slot swap: own staging loads landed, then block-wide visibility
      asm volatile("s_waitcnt vmcnt(0)" ::: "memory");
      __builtin_amdgcn_s_barrier();
    }
  }

  // epilogue: per-row (best, 2nd, idx); C layout: row = quad*4 + reg, col = lane&15
  #pragma unroll
  for (int mt = 0; mt < 8; mt++) {
    #pragma unroll
    for (int r = 0; r < 4; r++) {
      float d1 = 3.0e38f, d2 = 3.0e38f;
      int i1 = 0;
      #pragma unroll
      for (int nt = 0; nt < 4; nt++) {
        int lc = wn * 64 + nt * 16 + col;
        float d = wsqs[lc] - 2.0f * acc[mt][nt][r];
        int g = cb + lc;
        if (d < d1) { d2 = d1; d1 = d; i1 = g; }
        else if (d < d2) d2 = d;
      }
      #pragma unroll
      for (int m = 1; m < 16; m <<= 1) {
        float od1 = __shfl_xor(d1, m);
        int oi1 = __shfl_xor(i1, m);
        float od2 = __shfl_xor(d2, m);
        if (od1 < d1 || (od1 == d1 && oi1 < i1)) {
          d2 = fminf(d1, fminf(d2, od2));
          d1 = od1; i1 = oi1;
        } else {
          d2 = fminf(od1, fminf(d2, od2));
        }
      }
      if (col == 0) {
        int lr = wm * 128 + mt * 16 + quad * 4 + r;  // 0..255
        d1L[lr][wn] = d1;
        d2L[lr][wn] = d2;
        i1L[lr][wn] = i1;
      }
    }
  }
  __syncthreads();
  if (tid < 256) {
    float m1 = d1L[tid][0], m2 = d2L[tid][0];
    int mi = i1L[tid][0];
    #pragma unroll
    for (int w = 1; w < 4; w++) {
      float b1 = d1L[tid][w], b2 = d2L[tid][w];
      int bi = i1L[tid][w];
      if (b1 < m1 || (b1 == m1 && bi < mi)) { m2 = fminf(m1, b2); m1 = b1; mi = bi; }
      else { m2 = fminf(m2, fminf(b1, b2)); }
    }
    int o = bn * NTOT + bm * 256 + tid;
    ws[WS_CAND1 + o] = m1;
    ws[WS_CAND2 + o] = m2;
    ((int*)ws)[WS_CANDI + o] = mi;
  }
}

// ---------- pass2: merge candidates; idx, commit, flags; fused quant gather ----------
__global__ __launch_bounds__(256) void pass2_kernel(const float* __restrict__ W,
                                                    float* __restrict__ outQ,
                                                    float* __restrict__ outIdx, float* ws) {
  __shared__ int idx_s[256];
  int tid = threadIdx.x;
  int row = blockIdx.x * 256 + tid;
  const float* c1 = ws + WS_CAND1;
  const float* c2 = ws + WS_CAND2;
  const int* ci = (const int*)ws + WS_CANDI;
  float m1 = 3.0e38f, m2 = 3.0e38f;
  int mi = 0;
  #pragma unroll
  for (int b = 0; b < 4; b++) {
    int o = b * NTOT + row;
    float b1 = c1[o], b2 = c2[o];
    int bi = ci[o];
    if (b1 < m1 || (b1 == m1 && bi < mi)) { m2 = fminf(m1, b2); m1 = b1; mi = bi; }
    else { m2 = fminf(m2, fminf(b1, b2)); }
  }
  outIdx[row] = (float)mi;
  idx_s[tid] = mi;
  int* wsI = (int*)ws;
  if (m2 - m1 < TAU) {
    int p = atomicAdd(&wsI[WS_FLAGCNT], 1);
    wsI[WS_FLAGS + p] = row;
  }
  float partial = ws[WS_XSQ + row] + m1;
  #pragma unroll
  for (int m = 32; m >= 1; m >>= 1) partial += __shfl_xor(partial, m);
  if ((tid & 63) == 0) atomicAdd(&ws[WS_COMMIT], partial);
  __syncthreads();
  int wave = tid >> 6, lane = tid & 63;
  int rowBase = blockIdx.x * 256;
  #pragma unroll 4
  for (int i = 0; i < 64; i++) {
    int rl = wave * 64 + i;
    int ix = idx_s[rl];
    float4 v = ((const float4*)(W + (size_t)ix * DIMS))[lane];
    ((float4*)(outQ + (size_t)(rowBase + rl) * DIMS))[lane] = v;
  }
}

// ---------- f64 refinement (blocks 0..511) + fused scalar finalize (block 512) ----------
__global__ __launch_bounds__(256) void refine_kernel(const float* __restrict__ X,
                                                     const float* __restrict__ W,
                                                     float* __restrict__ outQ,
                                                     float* __restrict__ outIdx, float* ws,
                                                     const float* __restrict__ U,
                                                     float* __restrict__ out) {
  __shared__ float xs[DIMS];
  __shared__ double dm[256];
  __shared__ int im[256];
  __shared__ int chosen;
  int tid = threadIdx.x;
  if (blockIdx.x == 512) {
    // ---- finalize ----
    __shared__ float red[256];
    float s = 0.f;
    for (int e = tid; e < KCODES; e += 256) s += U[e] + 1e-5f;
    red[tid] = s;
    __syncthreads();
    for (int st = 128; st >= 1; st >>= 1) {
      if (tid < st) red[tid] += red[tid + st];
      __syncthreads();
    }
    float S = red[0];
    __syncthreads();
    float denom = fmaxf(S, 1e-5f * 1024.0f);
    float h = 0.f;
    for (int e = tid; e < KCODES; e += 256) {
      float p = (U[e] + 1e-5f) / denom;
      h += p * logf(p + 1e-5f);
    }
    red[tid] = h;
    __syncthreads();
    for (int st = 128; st >= 1; st >>= 1) {
      if (tid < st) red[tid] += red[tid + st];
      __syncthreads();
    }
    float H = -red[0] / 6.93147180559945f;  // ln(1024)
    __syncthreads();
    float m = ws[WS_COLSUM + tid] * (1.0f / 1024.0f);
    float var = ws[WS_COLSQ + tid] * (1.0f / 1024.0f) - m * m;
    float r = 0.05f - var;
    red[tid] = r > 0.f ? r : 0.f;
    __syncthreads();
    for (int st = 128; st >= 1; st >>= 1) {
      if (tid < st) red[tid] += red[tid + st];
      __syncthreads();
    }
    if (tid == 0) {
      float varloss = 1e-3f * (red[0] / 256.0f);
      float gap = H < 0.5f ? (0.5f - H) : (H > 0.9f ? (H - 0.9f) : 0.0f);
      float entloss = 0.1f * gap * gap;
      float commit = 0.25f * ws[WS_COMMIT] / 8388608.0f;
      float dec = 1e-3f * ws[WS_DECORR] / 65536.0f;
      float* sc = out + OUT_SCAL;
      sc[0] = commit + entloss + varloss + dec;
      sc[1] = commit;
      sc[2] = entloss;
      sc[3] = varloss;
      sc[4] = dec;
      sc[5] = H;
    }
    return;
  }
  const int* wsI = (const int*)ws;
  int cnt = wsI[WS_FLAGCNT];
  const int* list = wsI + WS_FLAGS;
  for (int f = blockIdx.x; f < cnt; f += 512) {
    int row = list[f];
    __syncthreads();
    if (tid < 64) ((float4*)xs)[tid] = ((const float4*)(X + (size_t)row * DIMS))[tid];
    __syncthreads();
    double bd = 1.0e300;
    int bi = 0;
    for (int jj = 0; jj < 4; jj++) {
      int c = tid + 256 * jj;
      double a0 = 0.0, a1 = 0.0, a2 = 0.0, a3 = 0.0;
      const float* wr = W + (size_t)c * DIMS;
      #pragma unroll 4
      for (int d4 = 0; d4 < 64; d4++) {
        float4 w = ((const float4*)wr)[d4];
        float4 x = ((const float4*)xs)[d4];
        double e0 = (double)x.x - (double)w.x;
        double e1 = (double)x.y - (double)w.y;
        double e2 = (double)x.z - (double)w.z;
        double e3 = (double)x.w - (double)w.w;
        a0 += e0 * e0; a1 += e1 * e1; a2 += e2 * e2; a3 += e3 * e3;
      }
      double s = (a0 + a1) + (a2 + a3);
      if (s < bd) { bd = s; bi = c; }
    }
    dm[tid] = bd; im[tid] = bi;
    __syncthreads();
    for (int st = 128; st >= 1; st >>= 1) {
      if (tid < st) {
        if (dm[tid + st] < dm[tid] || (dm[tid + st] == dm[tid] && im[tid + st] < im[tid])) {
          dm[tid] = dm[tid + st]; im[tid] = im[tid + st];
        }
      }
      __syncthreads();
    }
    if (tid == 0) { chosen = im[0]; outIdx[row] = (float)im[0]; }
    __syncthreads();
    int ix = chosen;
    if (tid < 64)
      ((float4*)(outQ + (size_t)row * DIMS))[tid] = ((const float4*)(W + (size_t)ix * DIMS))[tid];
  }
}

extern "C" void kernel_launch(void* const* d_in, const int* in_sizes, int n_in, void* d_out,
                              int out_size, void* d_ws, size_t ws_size, hipStream_t stream) {
  const float* X = (const float*)d_in[0];
  const float* W = (const float*)d_in[1];
  const float* U = (const float*)d_in[2];
  float* out = (float*)d_out;
  float* ws = (float*)d_ws;
  __bf16* Xp = (__bf16*)(out + OUT_Q);       // 33.55 MB, overwritten by pass2's gather
  __bf16* Wp2 = (__bf16*)(ws + WS_WP);       // 1 MB, fragment-ordered

  hipMemsetAsync(d_ws, 0, 139264, stream);
  prep_kernel<<<1192, 256, 0, stream>>>(X, W, Xp, Wp2, ws);
  pass1_kernel<<<512, 512, 0, stream>>>(Xp, Wp2, ws);
  pass2_kernel<<<NTOT / 256, 256, 0, stream>>>(W, out + OUT_Q, out + OUT_IDX, ws);
  refine_kernel<<<513, 256, 0, stream>>>(X, W, out + OUT_Q, out + OUT_IDX, ws, U, out);
}

// Round 3
// 232.067 us; speedup vs baseline: 1.0943x; 1.0215x over previous
//
#include <hip/hip_runtime.h>
#include <math.h>

#define DIMS   256
#define KCODES 1024
#define NTOT   32768
#define TAU    4.0e-4f   // 3-term split distance-compare error <~6e-5; 6x margin

typedef __bf16 bf16x8 __attribute__((ext_vector_type(8)));
typedef float  f32x4  __attribute__((ext_vector_type(4)));

// ---- workspace layout (float indices; int views share) ----
#define WS_COMMIT   0          // float atomic
#define WS_FLAGCNT  1          // int atomic
#define WS_DECORR   2          // float atomic
#define WS_COLSUM   16         // float[256]
#define WS_COLSQ    272        // float[256]
#define WS_WSQ      1024       // float[1024]  (atomic-accumulated)
#define WS_XSQ      2048       // float[32768] (atomic-accumulated)
// memset zero region: bytes [0, 139264) covers all of the above
#define WS_FLAGS    34816      // int[32768]
#define WS_CAND1    67584      // float[8*32768]
#define WS_CAND2    329728     // float[8*32768]
#define WS_CANDI    591872     // int[8*32768]
#define WS_WP       854016     // bf16[524288] = 1 MB, fragment-ordered W

// ---- output layout (floats) ----
#define OUT_Q    0
#define OUT_IDX  8388608
#define OUT_SCAL 8421376

// Fragment layout (both Xp and Wp2), bf16 elems:
//   frag(bt, kt, wv, t, hl) base = ((((bt*8+kt)*2+wv)*4+t)*2+hl)*512
//   element (lane = kq*16+lc, e) at base + lane*8 + e
//   holds hi/lo bf16 of src[row = bt*128+wv*64+t*16+lc][k = kt*32+kq*8+e]

// ---------- fused prep ----------
// blocks [0,1024): pack X | [1024,1056): pack W | [1056,1064): colstats | [1064,1320): cov
__global__ __launch_bounds__(256) void prep_kernel(const float* __restrict__ X,
                                                   const float* __restrict__ W,
                                                   __bf16* __restrict__ Xp,
                                                   __bf16* __restrict__ Wp2,
                                                   float* ws) {
  int b = blockIdx.x;
  int tid = threadIdx.x;
  if (b < 1056) {
    bool isW = b >= 1024;
    const float* src = isW ? W : X;
    __bf16* dst = isW ? Wp2 : Xp;
    int sqoff = isW ? WS_WSQ : WS_XSQ;
    int bb = isW ? b - 1024 : b;
    int kt = tid >> 5, mtl = (tid >> 4) & 1, lc = tid & 15;
    int row = bb * 32 + mtl * 16 + lc;
    int bt = row >> 7, c = row & 127;
    int wv = c >> 6, t = (c >> 4) & 3;
    size_t hibase = ((((size_t)(bt * 8 + kt) * 2 + wv) * 4 + t) * 2) * 512;
    const float* s = src + (size_t)row * DIMS + kt * 32;
    float sq = 0.f;
    #pragma unroll
    for (int kq = 0; kq < 4; kq++) {
      float4 u = *(const float4*)(s + kq * 8);
      float4 v = *(const float4*)(s + kq * 8 + 4);
      float f[8] = {u.x, u.y, u.z, u.w, v.x, v.y, v.z, v.w};
      bf16x8 hi, lo;
      #pragma unroll
      for (int e = 0; e < 8; e++) {
        __bf16 h = (__bf16)f[e];
        hi[e] = h;
        lo[e] = (__bf16)(f[e] - (float)h);
        sq = fmaf(f[e], f[e], sq);
      }
      size_t off = (size_t)(kq * 16 + lc) * 8;
      *(bf16x8*)&dst[hibase + off] = hi;
      *(bf16x8*)&dst[hibase + 512 + off] = lo;
    }
    atomicAdd(&ws[sqoff + row], sq);
  } else if (b < 1064) {
    // colstats: 8 blocks x 128 rows
    int d = tid;
    int r0 = (b - 1056) * 128;
    float s = 0.f, sq = 0.f;
    #pragma unroll 8
    for (int k = 0; k < 128; k++) {
      float v = W[(size_t)(r0 + k) * DIMS + d];
      s += v;
      sq = fmaf(v, v, sq);
    }
    atomicAdd(&ws[WS_COLSUM + d], s);
    atomicAdd(&ws[WS_COLSQ + d], sq);
  } else {
    // cov: 256 blocks x 1 column, self-contained means (full CU coverage)
    __shared__ float wi_s[KCODES];
    __shared__ float red2[256];
    __shared__ float miB;
    __shared__ float red[4];
    int i0 = b - 1064;
    #pragma unroll
    for (int q = 0; q < 4; q++) {
      int row = q * 256 + tid;
      wi_s[row] = W[(size_t)row * DIMS + i0];
    }
    __syncthreads();
    float pm = 0.f;
    #pragma unroll
    for (int q = 0; q < 4; q++) pm += wi_s[tid * 4 + q];
    red2[tid] = pm;
    __syncthreads();
    if (tid == 0) {
      float s = 0.f;
      for (int k = 0; k < 256; k++) s += red2[k];
      miB = s * (1.0f / 1024.0f);
    }
    int j = tid;
    float a0 = 0.f, sj = 0.f;
    for (int k = 0; k < KCODES; k += 4) {
      #pragma unroll
      for (int u = 0; u < 4; u++) {
        float wj = W[(size_t)(k + u) * DIMS + j];
        a0 = fmaf(wi_s[k + u], wj, a0);
        sj += wj;
      }
    }
    __syncthreads();  // miB ready
    const float inv = 1.0f / 1024.0f;
    float mj = sj * inv;
    float v = 0.f;
    float c0 = a0 * inv - miB * mj;
    if (i0 != j) v = c0 * c0;
    #pragma unroll
    for (int m = 32; m >= 1; m >>= 1) v += __shfl_xor(v, m);
    if ((j & 63) == 0) red[j >> 6] = v;
    __syncthreads();
    if (j == 0) atomicAdd(&ws[WS_DECORR], (red[0] + red[1]) + (red[2] + red[3]));
  }
}

// ---------- pass1: barrier-free all-register fragment GEMM, 3-term bf16 MFMA ----------
// 1D grid 2048, XCD-swizzled: bm=(l&7)*32+((l>>3)&31), bn=l>>8.  (proven 77.3 us)
__global__ __launch_bounds__(256, 2) void pass1_kernel(const __bf16* __restrict__ Xp,
                                                       const __bf16* __restrict__ Wp2,
                                                       float* ws) {
  __shared__ float wsqs[128];
  __shared__ float d1L[256];
  __shared__ float d2L[256];
  __shared__ int   i1L[256];

  int tid = threadIdx.x;
  int lane = tid & 63, wave = tid >> 6;
  int wm = wave >> 1, wn = wave & 1;
  int quad = lane >> 4, col = lane & 15;
  int l = blockIdx.x;
  int bm = (l & 7) * 32 + ((l >> 3) & 31);
  int bn = l >> 8;
  int rowBase = bm * 128, cb = bn * 128;

  if (tid < 128) wsqs[tid] = ws[WS_WSQ + cb + tid];

  f32x4 acc[4][4];
  #pragma unroll
  for (int i = 0; i < 4; i++)
    #pragma unroll
    for (int j = 0; j < 4; j++) acc[i][j] = (f32x4){0.f, 0.f, 0.f, 0.f};

  // bf16x8-unit strides: kt=1024, frag t=128, hl=64
  const bf16x8* ab = (const bf16x8*)(Xp + (size_t)bm * 65536 + wm * 4096) + lane;
  const bf16x8* bb = (const bf16x8*)(Wp2 + (size_t)bn * 65536 + wn * 4096) + lane;

  bf16x8 Af[2][8], Bf[2][8];  // [buf][t*2+hl]
  #pragma unroll
  for (int f = 0; f < 4; f++) {
    Af[0][f * 2] = ab[f * 128];
    Af[0][f * 2 + 1] = ab[f * 128 + 64];
    Bf[0][f * 2] = bb[f * 128];
    Bf[0][f * 2 + 1] = bb[f * 128 + 64];
  }
  #pragma unroll
  for (int kt = 0; kt < 8; kt++) {
    const int cur = kt & 1, nxt = cur ^ 1;
    if (kt < 7) {
      const bf16x8* an = ab + (kt + 1) * 1024;
      const bf16x8* bv = bb + (kt + 1) * 1024;
      #pragma unroll
      for (int f = 0; f < 4; f++) {
        Af[nxt][f * 2] = an[f * 128];
        Af[nxt][f * 2 + 1] = an[f * 128 + 64];
        Bf[nxt][f * 2] = bv[f * 128];
        Bf[nxt][f * 2 + 1] = bv[f * 128 + 64];
      }
    }
    #pragma unroll
    for (int nt = 0; nt < 4; nt++) {
      #pragma unroll
      for (int mt = 0; mt < 4; mt++) {
        acc[mt][nt] = __builtin_amdgcn_mfma_f32_16x16x32_bf16(Af[cur][mt * 2], Bf[cur][nt * 2], acc[mt][nt], 0, 0, 0);
        acc[mt][nt] = __builtin_amdgcn_mfma_f32_16x16x32_bf16(Af[cur][mt * 2], Bf[cur][nt * 2 + 1], acc[mt][nt], 0, 0, 0);
        acc[mt][nt] = __builtin_amdgcn_mfma_f32_16x16x32_bf16(Af[cur][mt * 2 + 1], Bf[cur][nt * 2], acc[mt][nt], 0, 0, 0);
      }
    }
  }
  __syncthreads();  // wsqs visibility for all waves

  // epilogue: per-row (best, 2nd, idx); C layout: row = quad*4 + reg, col = lane&15
  #pragma unroll
  for (int mt = 0; mt < 4; mt++) {
    #pragma unroll
    for (int r = 0; r < 4; r++) {
      float d1 = 3.0e38f, d2 = 3.0e38f;
      int i1 = 0;
      #pragma unroll
      for (int nt = 0; nt < 4; nt++) {
        int lc = wn * 64 + nt * 16 + col;
        float d = wsqs[lc] - 2.0f * acc[mt][nt][r];
        int g = cb + lc;
        if (d < d1) { d2 = d1; d1 = d; i1 = g; }
        else if (d < d2) d2 = d;
      }
      #pragma unroll
      for (int m = 1; m < 16; m <<= 1) {
        float od1 = __shfl_xor(d1, m);
        int oi1 = __shfl_xor(i1, m);
        float od2 = __shfl_xor(d2, m);
        if (od1 < d1 || (od1 == d1 && oi1 < i1)) {
          d2 = fminf(d1, fminf(d2, od2));
          d1 = od1; i1 = oi1;
        } else {
          d2 = fminf(od1, fminf(d2, od2));
        }
      }
      if (col == 0) {
        int lr = wm * 64 + mt * 16 + quad * 4 + r;
        d1L[lr * 2 + wn] = d1;
        d2L[lr * 2 + wn] = d2;
        i1L[lr * 2 + wn] = i1;
      }
    }
  }
  __syncthreads();
  if (tid < 128) {
    float a1 = d1L[tid * 2], a2 = d2L[tid * 2];
    int ai = i1L[tid * 2];
    float b1 = d1L[tid * 2 + 1], b2 = d2L[tid * 2 + 1];
    int bi = i1L[tid * 2 + 1];
    float m1, m2; int mi;
    if (b1 < a1 || (b1 == a1 && bi < ai)) { m1 = b1; mi = bi; m2 = fminf(a1, b2); }
    else { m1 = a1; mi = ai; m2 = fminf(b1, a2); }
    int o = bn * NTOT + rowBase + tid;
    ws[WS_CAND1 + o] = m1;
    ws[WS_CAND2 + o] = m2;
    ((int*)ws)[WS_CANDI + o] = mi;
  }
}

// ---------- pass2 v2: 512 blocks x 64 rows — spread gather/write across all CUs ----------
// 2-min merge with (dist,idx) lex tie-break is associative; pair-merge + sequential
// LDS merge gives identical results to the old sequential b=0..7 loop.
__global__ __launch_bounds__(256) void pass2_kernel(const float* __restrict__ W,
                                                    float* __restrict__ outQ,
                                                    float* __restrict__ outIdx, float* ws) {
  __shared__ float p1L[4][64];
  __shared__ float p2L[4][64];
  __shared__ int   piL[4][64];
  __shared__ int   idx_s[64];
  int tid = threadIdx.x;
  int r0 = blockIdx.x * 64;
  int grp = tid >> 6, rl = tid & 63;
  int row = r0 + rl;
  const float* c1 = ws + WS_CAND1;
  const float* c2 = ws + WS_CAND2;
  const int* ci = (const int*)ws + WS_CANDI;
  // pair-merge slots (2*grp, 2*grp+1)
  {
    int oa = (2 * grp) * NTOT + row;
    int ob = (2 * grp + 1) * NTOT + row;
    float a1 = c1[oa], a2 = c2[oa];
    int ai = ci[oa];
    float b1 = c1[ob], b2 = c2[ob];
    int bi = ci[ob];
    float m1, m2; int mi;
    if (b1 < a1 || (b1 == a1 && bi < ai)) { m1 = b1; mi = bi; m2 = fminf(a1, b2); }
    else { m1 = a1; mi = ai; m2 = fminf(a2, b1); }
    p1L[grp][rl] = m1;
    p2L[grp][rl] = m2;
    piL[grp][rl] = mi;
  }
  __syncthreads();
  if (tid < 64) {
    float m1 = p1L[0][tid], m2 = p2L[0][tid];
    int mi = piL[0][tid];
    #pragma unroll
    for (int w = 1; w < 4; w++) {
      float b1 = p1L[w][tid], b2 = p2L[w][tid];
      int bi = piL[w][tid];
      if (b1 < m1 || (b1 == m1 && bi < mi)) { m2 = fminf(m1, b2); m1 = b1; mi = bi; }
      else { m2 = fminf(m2, b1); }
    }
    int rw = r0 + tid;
    outIdx[rw] = (float)mi;
    idx_s[tid] = mi;
    int* wsI = (int*)ws;
    if (m2 - m1 < TAU) {
      int p = atomicAdd(&wsI[WS_FLAGCNT], 1);
      wsI[WS_FLAGS + p] = rw;
    }
    float partial = ws[WS_XSQ + rw] + m1;
    #pragma unroll
    for (int m = 32; m >= 1; m >>= 1) partial += __shfl_xor(partial, m);
    if (tid == 0) atomicAdd(&ws[WS_COMMIT], partial);
  }
  __syncthreads();
  int wave = tid >> 6, lane = tid & 63;
  #pragma unroll 4
  for (int i = 0; i < 16; i++) {
    int rr = wave * 16 + i;
    int ix = idx_s[rr];
    float4 v = ((const float4*)(W + (size_t)ix * DIMS))[lane];
    ((float4*)(outQ + (size_t)(r0 + rr) * DIMS))[lane] = v;
  }
}

// ---------- f64 refinement (blocks 0..511) + fused scalar finalize (block 512) ----------
__global__ __launch_bounds__(256) void refine_kernel(const float* __restrict__ X,
                                                     const float* __restrict__ W,
                                                     float* __restrict__ outQ,
                                                     float* __restrict__ outIdx, float* ws,
                                                     const float* __restrict__ U,
                                                     float* __restrict__ out) {
  __shared__ float xs[DIMS];
  __shared__ double dm[256];
  __shared__ int im[256];
  __shared__ int chosen;
  int tid = threadIdx.x;
  if (blockIdx.x == 512) {
    // ---- finalize ----
    __shared__ float red[256];
    float s = 0.f;
    for (int e = tid; e < KCODES; e += 256) s += U[e] + 1e-5f;
    red[tid] = s;
    __syncthreads();
    for (int st = 128; st >= 1; st >>= 1) {
      if (tid < st) red[tid] += red[tid + st];
      __syncthreads();
    }
    float S = red[0];
    __syncthreads();
    float denom = fmaxf(S, 1e-5f * 1024.0f);
    float h = 0.f;
    for (int e = tid; e < KCODES; e += 256) {
      float p = (U[e] + 1e-5f) / denom;
      h += p * logf(p + 1e-5f);
    }
    red[tid] = h;
    __syncthreads();
    for (int st = 128; st >= 1; st >>= 1) {
      if (tid < st) red[tid] += red[tid + st];
      __syncthreads();
    }
    float H = -red[0] / 6.93147180559945f;  // ln(1024)
    __syncthreads();
    float m = ws[WS_COLSUM + tid] * (1.0f / 1024.0f);
    float var = ws[WS_COLSQ + tid] * (1.0f / 1024.0f) - m * m;
    float r = 0.05f - var;
    red[tid] = r > 0.f ? r : 0.f;
    __syncthreads();
    for (int st = 128; st >= 1; st >>= 1) {
      if (tid < st) red[tid] += red[tid + st];
      __syncthreads();
    }
    if (tid == 0) {
      float varloss = 1e-3f * (red[0] / 256.0f);
      float gap = H < 0.5f ? (0.5f - H) : (H > 0.9f ? (H - 0.9f) : 0.0f);
      float entloss = 0.1f * gap * gap;
      float commit = 0.25f * ws[WS_COMMIT] / 8388608.0f;
      float dec = 1e-3f * ws[WS_DECORR] / 65536.0f;
      float* sc = out + OUT_SCAL;
      sc[0] = commit + entloss + varloss + dec;
      sc[1] = commit;
      sc[2] = entloss;
      sc[3] = varloss;
      sc[4] = dec;
      sc[5] = H;
    }
    return;
  }
  const int* wsI = (const int*)ws;
  int cnt = wsI[WS_FLAGCNT];
  const int* list = wsI + WS_FLAGS;
  for (int f = blockIdx.x; f < cnt; f += 512) {
    int row = list[f];
    __syncthreads();
    if (tid < 64) ((float4*)xs)[tid] = ((const float4*)(X + (size_t)row * DIMS))[tid];
    __syncthreads();
    double bd = 1.0e300;
    int bi = 0;
    for (int jj = 0; jj < 4; jj++) {
      int c = tid + 256 * jj;
      double a0 = 0.0, a1 = 0.0, a2 = 0.0, a3 = 0.0;
      const float* wr = W + (size_t)c * DIMS;
      #pragma unroll 4
      for (int d4 = 0; d4 < 64; d4++) {
        float4 w = ((const float4*)wr)[d4];
        float4 x = ((const float4*)xs)[d4];
        double e0 = (double)x.x - (double)w.x;
        double e1 = (double)x.y - (double)w.y;
        double e2 = (double)x.z - (double)w.z;
        double e3 = (double)x.w - (double)w.w;
        a0 += e0 * e0; a1 += e1 * e1; a2 += e2 * e2; a3 += e3 * e3;
      }
      double s = (a0 + a1) + (a2 + a3);
      if (s < bd) { bd = s; bi = c; }
    }
    dm[tid] = bd; im[tid] = bi;
    __syncthreads();
    for (int st = 128; st >= 1; st >>= 1) {
      if (tid < st) {
        if (dm[tid + st] < dm[tid] || (dm[tid + st] == dm[tid] && im[tid + st] < im[tid])) {
          dm[tid] = dm[tid + st]; im[tid] = im[tid + st];
        }
      }
      __syncthreads();
    }
    if (tid == 0) { chosen = im[0]; outIdx[row] = (float)im[0]; }
    __syncthreads();
    int ix = chosen;
    if (tid < 64)
      ((float4*)(outQ + (size_t)row * DIMS))[tid] = ((const float4*)(W + (size_t)ix * DIMS))[tid];
  }
}

extern "C" void kernel_launch(void* const* d_in, const int* in_sizes, int n_in, void* d_out,
                              int out_size, void* d_ws, size_t ws_size, hipStream_t stream) {
  const float* X = (const float*)d_in[0];
  const float* W = (const float*)d_in[1];
  const float* U = (const float*)d_in[2];
  float* out = (float*)d_out;
  float* ws = (float*)d_ws;
  __bf16* Xp = (__bf16*)(out + OUT_Q);       // 33.55 MB, overwritten by pass2's gather
  __bf16* Wp2 = (__bf16*)(ws + WS_WP);       // 1 MB, fragment-ordered

  hipMemsetAsync(d_ws, 0, 139264, stream);
  prep_kernel<<<1320, 256, 0, stream>>>(X, W, Xp, Wp2, ws);
  pass1_kernel<<<2048, 256, 0, stream>>>(Xp, Wp2, ws);
  pass2_kernel<<<512, 256, 0, stream>>>(W, out + OUT_Q, out + OUT_IDX, ws);
  refine_kernel<<<513, 256, 0, stream>>>(X, W, out + OUT_Q, out + OUT_IDX, ws, U, out);
}

// Round 4
// 229.191 us; speedup vs baseline: 1.1081x; 1.0125x over previous
//
#include <hip/hip_runtime.h>
#include <math.h>

#define DIMS   256
#define KCODES 1024
#define NTOT   32768
#define TAU    4.0e-4f   // 3-term split distance-compare error <~6e-5; 6x margin

typedef __bf16 bf16x8 __attribute__((ext_vector_type(8)));
typedef float  f32x4  __attribute__((ext_vector_type(4)));

// ---- workspace layout (float indices; int views share) ----
#define WS_COMMIT   0          // float atomic
#define WS_FLAGCNT  1          // int atomic
#define WS_DECORR   2          // float atomic
#define WS_COLSUM   16         // float[256]  (direct-stored by cov blocks)
#define WS_COLSQ    272        // float[256]  (direct-stored by cov blocks)
#define WS_WSQ      1024       // float[1024]  (direct-stored by W-pack blocks)
#define WS_XSQ      2048       // float[32768] (direct-stored by X-pack blocks)
// memset zero region: bytes [0, 12) only (COMMIT, FLAGCNT, DECORR)
#define WS_FLAGS    34816      // int[32768]
#define WS_CAND1    67584      // float[8*32768]
#define WS_CAND2    329728     // float[8*32768]
#define WS_CANDI    591872     // int[8*32768]
#define WS_WP       854016     // bf16[524288] = 1 MB, fragment-ordered W

// ---- output layout (floats) ----
#define OUT_Q    0
#define OUT_IDX  8388608
#define OUT_SCAL 8421376

// Fragment layout (both Xp and Wp2), bf16 elems:
//   frag(bt, kt, wv, t, hl) base = ((((bt*8+kt)*2+wv)*4+t)*2+hl)*512
//   element (lane = kq*16+lc, e) at base + lane*8 + e
//   holds hi/lo bf16 of src[row = bt*128+wv*64+t*16+lc][k = kt*32+kq*8+e]

// ---------- fused prep ----------
// blocks [0,1024): pack X | [1024,1056): pack W | [1056,1312): cov+colstats
__global__ __launch_bounds__(256) void prep_kernel(const float* __restrict__ X,
                                                   const float* __restrict__ W,
                                                   __bf16* __restrict__ Xp,
                                                   __bf16* __restrict__ Wp2,
                                                   float* ws) {
  int b = blockIdx.x;
  int tid = threadIdx.x;
  if (b < 1056) {
    __shared__ float sqred[256];
    bool isW = b >= 1024;
    const float* src = isW ? W : X;
    __bf16* dst = isW ? Wp2 : Xp;
    int sqoff = isW ? WS_WSQ : WS_XSQ;
    int bb = isW ? b - 1024 : b;
    int kt = tid >> 5, mtl = (tid >> 4) & 1, lc = tid & 15;
    int row = bb * 32 + mtl * 16 + lc;
    int bt = row >> 7, c = row & 127;
    int wv = c >> 6, t = (c >> 4) & 3;
    size_t hibase = ((((size_t)(bt * 8 + kt) * 2 + wv) * 4 + t) * 2) * 512;
    const float* s = src + (size_t)row * DIMS + kt * 32;
    float sq = 0.f;
    #pragma unroll
    for (int kq = 0; kq < 4; kq++) {
      float4 u = *(const float4*)(s + kq * 8);
      float4 v = *(const float4*)(s + kq * 8 + 4);
      float f[8] = {u.x, u.y, u.z, u.w, v.x, v.y, v.z, v.w};
      bf16x8 hi, lo;
      #pragma unroll
      for (int e = 0; e < 8; e++) {
        __bf16 h = (__bf16)f[e];
        hi[e] = h;
        lo[e] = (__bf16)(f[e] - (float)h);
        sq = fmaf(f[e], f[e], sq);
      }
      size_t off = (size_t)(kq * 16 + lc) * 8;
      *(bf16x8*)&dst[hibase + off] = hi;
      *(bf16x8*)&dst[hibase + 512 + off] = lo;
    }
    // block-owned row-norm reduce (rows bb*32..bb*32+31): contributors are the
    // 8 kt-threads sharing (tid&31). Direct store -> no memset dependency.
    sqred[tid] = sq;
    __syncthreads();
    if (tid < 32) {
      float s8 = 0.f;
      #pragma unroll
      for (int k = 0; k < 8; k++) s8 += sqred[k * 32 + tid];
      ws[sqoff + bb * 32 + tid] = s8;
    }
  } else {
    // cov + colstats: 256 blocks x 1 column, self-contained means.
    // Each block owns column j=tid for the cov row-pass AND column i0 overall;
    // colsum/colsq for column j are direct-stored by the block with i0==...:
    // NOTE each j in 0..255 is owned by exactly one block (i0 == j is NOT the
    // owner relation; every block computes sj/sqj for all j=tid. To keep a
    // unique owner, block with i0 stores colsum/colsq for column i0 only.)
    __shared__ float wi_s[KCODES];
    __shared__ float red2[256];
    __shared__ float miB;
    __shared__ float red[4];
    int i0 = b - 1056;
    #pragma unroll
    for (int q = 0; q < 4; q++) {
      int row = q * 256 + tid;
      wi_s[row] = W[(size_t)row * DIMS + i0];
    }
    __syncthreads();
    float pm = 0.f;
    #pragma unroll
    for (int q = 0; q < 4; q++) pm += wi_s[tid * 4 + q];
    red2[tid] = pm;
    __syncthreads();
    if (tid == 0) {
      float s = 0.f;
      for (int k = 0; k < 256; k++) s += red2[k];
      miB = s * (1.0f / 1024.0f);
    }
    int j = tid;
    float a0 = 0.f, sj = 0.f, sqj = 0.f;
    for (int k = 0; k < KCODES; k += 4) {
      #pragma unroll
      for (int u = 0; u < 4; u++) {
        float wj = W[(size_t)(k + u) * DIMS + j];
        a0 = fmaf(wi_s[k + u], wj, a0);
        sj += wj;
        sqj = fmaf(wj, wj, sqj);
      }
    }
    // column i0's stats: the lane with j==i0 has them; store once per block.
    if (j == i0) {
      ws[WS_COLSUM + i0] = sj;
      ws[WS_COLSQ + i0] = sqj;
    }
    __syncthreads();  // miB ready
    const float inv = 1.0f / 1024.0f;
    float mj = sj * inv;
    float v = 0.f;
    float c0 = a0 * inv - miB * mj;
    if (i0 != j) v = c0 * c0;
    #pragma unroll
    for (int m = 32; m >= 1; m >>= 1) v += __shfl_xor(v, m);
    if ((j & 63) == 0) red[j >> 6] = v;
    __syncthreads();
    if (j == 0) atomicAdd(&ws[WS_DECORR], (red[0] + red[1]) + (red[2] + red[3]));
  }
}

// ---------- pass1: barrier-free all-register fragment GEMM, 3-term bf16 MFMA ----------
// 1D grid 2048. L2-resident XCD swizzle: XCD x runs j=0..255 in order; the first
// 128 j's span only 16 bm x 8 bn -> concurrent footprint A 2.1MB + B 1MB < 4MB L2.
__global__ __launch_bounds__(256, 2) void pass1_kernel(const __bf16* __restrict__ Xp,
                                                       const __bf16* __restrict__ Wp2,
                                                       float* ws) {
  __shared__ float wsqs[128];
  __shared__ float d1L[256];
  __shared__ float d2L[256];
  __shared__ int   i1L[256];

  int tid = threadIdx.x;
  int lane = tid & 63, wave = tid >> 6;
  int wm = wave >> 1, wn = wave & 1;
  int quad = lane >> 4, col = lane & 15;
  int l = blockIdx.x;
  int x = l & 7;           // XCD
  int j = l >> 3;          // 0..255 within XCD
  int bm = x * 32 + (j & 15) + (j >> 7) * 16;   // 16-bm window per 128 blocks
  int bn = (j >> 4) & 7;
  int rowBase = bm * 128, cb = bn * 128;

  if (tid < 128) wsqs[tid] = ws[WS_WSQ + cb + tid];

  f32x4 acc[4][4];
  #pragma unroll
  for (int i = 0; i < 4; i++)
    #pragma unroll
    for (int jj = 0; jj < 4; jj++) acc[i][jj] = (f32x4){0.f, 0.f, 0.f, 0.f};

  // bf16x8-unit strides: kt=1024, frag t=128, hl=64
  const bf16x8* ab = (const bf16x8*)(Xp + (size_t)bm * 65536 + wm * 4096) + lane;
  const bf16x8* bb = (const bf16x8*)(Wp2 + (size_t)bn * 65536 + wn * 4096) + lane;

  bf16x8 Af[2][8], Bf[2][8];  // [buf][t*2+hl]
  #pragma unroll
  for (int f = 0; f < 4; f++) {
    Af[0][f * 2] = ab[f * 128];
    Af[0][f * 2 + 1] = ab[f * 128 + 64];
    Bf[0][f * 2] = bb[f * 128];
    Bf[0][f * 2 + 1] = bb[f * 128 + 64];
  }
  #pragma unroll
  for (int kt = 0; kt < 8; kt++) {
    const int cur = kt & 1, nxt = cur ^ 1;
    if (kt < 7) {
      const bf16x8* an = ab + (kt + 1) * 1024;
      const bf16x8* bv = bb + (kt + 1) * 1024;
      #pragma unroll
      for (int f = 0; f < 4; f++) {
        Af[nxt][f * 2] = an[f * 128];
        Af[nxt][f * 2 + 1] = an[f * 128 + 64];
        Bf[nxt][f * 2] = bv[f * 128];
        Bf[nxt][f * 2 + 1] = bv[f * 128 + 64];
      }
    }
    #pragma unroll
    for (int nt = 0; nt < 4; nt++) {
      #pragma unroll
      for (int mt = 0; mt < 4; mt++) {
        acc[mt][nt] = __builtin_amdgcn_mfma_f32_16x16x32_bf16(Af[cur][mt * 2], Bf[cur][nt * 2], acc[mt][nt], 0, 0, 0);
        acc[mt][nt] = __builtin_amdgcn_mfma_f32_16x16x32_bf16(Af[cur][mt * 2], Bf[cur][nt * 2 + 1], acc[mt][nt], 0, 0, 0);
        acc[mt][nt] = __builtin_amdgcn_mfma_f32_16x16x32_bf16(Af[cur][mt * 2 + 1], Bf[cur][nt * 2], acc[mt][nt], 0, 0, 0);
      }
    }
  }
  __syncthreads();  // wsqs visibility for all waves

  // epilogue: per-row (best, 2nd, idx); C layout: row = quad*4 + reg, col = lane&15
  #pragma unroll
  for (int mt = 0; mt < 4; mt++) {
    #pragma unroll
    for (int r = 0; r < 4; r++) {
      float d1 = 3.0e38f, d2 = 3.0e38f;
      int i1 = 0;
      #pragma unroll
      for (int nt = 0; nt < 4; nt++) {
        int lc = wn * 64 + nt * 16 + col;
        float d = wsqs[lc] - 2.0f * acc[mt][nt][r];
        int g = cb + lc;
        if (d < d1) { d2 = d1; d1 = d; i1 = g; }
        else if (d < d2) d2 = d;
      }
      #pragma unroll
      for (int m = 1; m < 16; m <<= 1) {
        float od1 = __shfl_xor(d1, m);
        int oi1 = __shfl_xor(i1, m);
        float od2 = __shfl_xor(d2, m);
        if (od1 < d1 || (od1 == d1 && oi1 < i1)) {
          d2 = fminf(d1, fminf(d2, od2));
          d1 = od1; i1 = oi1;
        } else {
          d2 = fminf(od1, fminf(d2, od2));
        }
      }
      if (col == 0) {
        int lr = wm * 64 + mt * 16 + quad * 4 + r;
        d1L[lr * 2 + wn] = d1;
        d2L[lr * 2 + wn] = d2;
        i1L[lr * 2 + wn] = i1;
      }
    }
  }
  __syncthreads();
  if (tid < 128) {
    float a1 = d1L[tid * 2], a2 = d2L[tid * 2];
    int ai = i1L[tid * 2];
    float b1 = d1L[tid * 2 + 1], b2 = d2L[tid * 2 + 1];
    int bi = i1L[tid * 2 + 1];
    float m1, m2; int mi;
    if (b1 < a1 || (b1 == a1 && bi < ai)) { m1 = b1; mi = bi; m2 = fminf(a1, b2); }
    else { m1 = a1; mi = ai; m2 = fminf(b1, a2); }
    int o = bn * NTOT + rowBase + tid;
    ws[WS_CAND1 + o] = m1;
    ws[WS_CAND2 + o] = m2;
    ((int*)ws)[WS_CANDI + o] = mi;
  }
}

// ---------- pass2: 512 blocks x 64 rows — spread gather/write across all CUs ----------
__global__ __launch_bounds__(256) void pass2_kernel(const float* __restrict__ W,
                                                    float* __restrict__ outQ,
                                                    float* __restrict__ outIdx, float* ws) {
  __shared__ float p1L[4][64];
  __shared__ float p2L[4][64];
  __shared__ int   piL[4][64];
  __shared__ int   idx_s[64];
  int tid = threadIdx.x;
  int r0 = blockIdx.x * 64;
  int grp = tid >> 6, rl = tid & 63;
  int row = r0 + rl;
  const float* c1 = ws + WS_CAND1;
  const float* c2 = ws + WS_CAND2;
  const int* ci = (const int*)ws + WS_CANDI;
  // pair-merge slots (2*grp, 2*grp+1)
  {
    int oa = (2 * grp) * NTOT + row;
    int ob = (2 * grp + 1) * NTOT + row;
    float a1 = c1[oa], a2 = c2[oa];
    int ai = ci[oa];
    float b1 = c1[ob], b2 = c2[ob];
    int bi = ci[ob];
    float m1, m2; int mi;
    if (b1 < a1 || (b1 == a1 && bi < ai)) { m1 = b1; mi = bi; m2 = fminf(a1, b2); }
    else { m1 = a1; mi = ai; m2 = fminf(a2, b1); }
    p1L[grp][rl] = m1;
    p2L[grp][rl] = m2;
    piL[grp][rl] = mi;
  }
  __syncthreads();
  if (tid < 64) {
    float m1 = p1L[0][tid], m2 = p2L[0][tid];
    int mi = piL[0][tid];
    #pragma unroll
    for (int w = 1; w < 4; w++) {
      float b1 = p1L[w][tid], b2 = p2L[w][tid];
      int bi = piL[w][tid];
      if (b1 < m1 || (b1 == m1 && bi < mi)) { m2 = fminf(m1, b2); m1 = b1; mi = bi; }
      else { m2 = fminf(m2, b1); }
    }
    int rw = r0 + tid;
    outIdx[rw] = (float)mi;
    idx_s[tid] = mi;
    int* wsI = (int*)ws;
    if (m2 - m1 < TAU) {
      int p = atomicAdd(&wsI[WS_FLAGCNT], 1);
      wsI[WS_FLAGS + p] = rw;
    }
    float partial = ws[WS_XSQ + rw] + m1;
    #pragma unroll
    for (int m = 32; m >= 1; m >>= 1) partial += __shfl_xor(partial, m);
    if (tid == 0) atomicAdd(&ws[WS_COMMIT], partial);
  }
  __syncthreads();
  int wave = tid >> 6, lane = tid & 63;
  #pragma unroll 4
  for (int i = 0; i < 16; i++) {
    int rr = wave * 16 + i;
    int ix = idx_s[rr];
    float4 v = ((const float4*)(W + (size_t)ix * DIMS))[lane];
    ((float4*)(outQ + (size_t)(r0 + rr) * DIMS))[lane] = v;
  }
}

// ---------- f64 refinement (blocks 0..511) + fused scalar finalize (block 512) ----------
__global__ __launch_bounds__(256) void refine_kernel(const float* __restrict__ X,
                                                     const float* __restrict__ W,
                                                     float* __restrict__ outQ,
                                                     float* __restrict__ outIdx, float* ws,
                                                     const float* __restrict__ U,
                                                     float* __restrict__ out) {
  __shared__ float xs[DIMS];
  __shared__ double dm[256];
  __shared__ int im[256];
  __shared__ int chosen;
  int tid = threadIdx.x;
  if (blockIdx.x == 512) {
    // ---- finalize ----
    __shared__ float red[256];
    float s = 0.f;
    for (int e = tid; e < KCODES; e += 256) s += U[e] + 1e-5f;
    red[tid] = s;
    __syncthreads();
    for (int st = 128; st >= 1; st >>= 1) {
      if (tid < st) red[tid] += red[tid + st];
      __syncthreads();
    }
    float S = red[0];
    __syncthreads();
    float denom = fmaxf(S, 1e-5f * 1024.0f);
    float h = 0.f;
    for (int e = tid; e < KCODES; e += 256) {
      float p = (U[e] + 1e-5f) / denom;
      h += p * logf(p + 1e-5f);
    }
    red[tid] = h;
    __syncthreads();
    for (int st = 128; st >= 1; st >>= 1) {
      if (tid < st) red[tid] += red[tid + st];
      __syncthreads();
    }
    float H = -red[0] / 6.93147180559945f;  // ln(1024)
    __syncthreads();
    float m = ws[WS_COLSUM + tid] * (1.0f / 1024.0f);
    float var = ws[WS_COLSQ + tid] * (1.0f / 1024.0f) - m * m;
    float r = 0.05f - var;
    red[tid] = r > 0.f ? r : 0.f;
    __syncthreads();
    for (int st = 128; st >= 1; st >>= 1) {
      if (tid < st) red[tid] += red[tid + st];
      __syncthreads();
    }
    if (tid == 0) {
      float varloss = 1e-3f * (red[0] / 256.0f);
      float gap = H < 0.5f ? (0.5f - H) : (H > 0.9f ? (H - 0.9f) : 0.0f);
      float entloss = 0.1f * gap * gap;
      float commit = 0.25f * ws[WS_COMMIT] / 8388608.0f;
      float dec = 1e-3f * ws[WS_DECORR] / 65536.0f;
      float* sc = out + OUT_SCAL;
      sc[0] = commit + entloss + varloss + dec;
      sc[1] = commit;
      sc[2] = entloss;
      sc[3] = varloss;
      sc[4] = dec;
      sc[5] = H;
    }
    return;
  }
  const int* wsI = (const int*)ws;
  int cnt = wsI[WS_FLAGCNT];
  const int* list = wsI + WS_FLAGS;
  for (int f = blockIdx.x; f < cnt; f += 512) {
    int row = list[f];
    __syncthreads();
    if (tid < 64) ((float4*)xs)[tid] = ((const float4*)(X + (size_t)row * DIMS))[tid];
    __syncthreads();
    double bd = 1.0e300;
    int bi = 0;
    for (int jj = 0; jj < 4; jj++) {
      int c = tid + 256 * jj;
      double a0 = 0.0, a1 = 0.0, a2 = 0.0, a3 = 0.0;
      const float* wr = W + (size_t)c * DIMS;
      #pragma unroll 4
      for (int d4 = 0; d4 < 64; d4++) {
        float4 w = ((const float4*)wr)[d4];
        float4 x = ((const float4*)xs)[d4];
        double e0 = (double)x.x - (double)w.x;
        double e1 = (double)x.y - (double)w.y;
        double e2 = (double)x.z - (double)w.z;
        double e3 = (double)x.w - (double)w.w;
        a0 += e0 * e0; a1 += e1 * e1; a2 += e2 * e2; a3 += e3 * e3;
      }
      double s = (a0 + a1) + (a2 + a3);
      if (s < bd) { bd = s; bi = c; }
    }
    dm[tid] = bd; im[tid] = bi;
    __syncthreads();
    for (int st = 128; st >= 1; st >>= 1) {
      if (tid < st) {
        if (dm[tid + st] < dm[tid] || (dm[tid + st] == dm[tid] && im[tid + st] < im[tid])) {
          dm[tid] = dm[tid + st]; im[tid] = im[tid + st];
        }
      }
      __syncthreads();
    }
    if (tid == 0) { chosen = im[0]; outIdx[row] = (float)im[0]; }
    __syncthreads();
    int ix = chosen;
    if (tid < 64)
      ((float4*)(outQ + (size_t)row * DIMS))[tid] = ((const float4*)(W + (size_t)ix * DIMS))[tid];
  }
}

extern "C" void kernel_launch(void* const* d_in, const int* in_sizes, int n_in, void* d_out,
                              int out_size, void* d_ws, size_t ws_size, hipStream_t stream) {
  const float* X = (const float*)d_in[0];
  const float* W = (const float*)d_in[1];
  const float* U = (const float*)d_in[2];
  float* out = (float*)d_out;
  float* ws = (float*)d_ws;
  __bf16* Xp = (__bf16*)(out + OUT_Q);       // 33.55 MB, overwritten by pass2's gather
  __bf16* Wp2 = (__bf16*)(ws + WS_WP);       // 1 MB, fragment-ordered

  hipMemsetAsync(d_ws, 0, 12, stream);       // COMMIT, FLAGCNT, DECORR only
  prep_kernel<<<1312, 256, 0, stream>>>(X, W, Xp, Wp2, ws);
  pass1_kernel<<<2048, 256, 0, stream>>>(Xp, Wp2, ws);
  pass2_kernel<<<512, 256, 0, stream>>>(W, out + OUT_Q, out + OUT_IDX, ws);
  refine_kernel<<<513, 256, 0, stream>>>(X, W, out + OUT_Q, out + OUT_IDX, ws, U, out);
}